// Round 8
// baseline (1578.119 us; speedup 1.0000x reference)
//
#include <hip/hip_runtime.h>
#include <hip/hip_bf16.h>

// DepthRouteNet — round 7: world model (consistent with ALL 8 observations):
// all inputs f32, OUTPUT BUFFER F32, harness compares vs bf16-rounded np ref
// (threshold 2e-2). R6/7's exact-1.0 error = bf16 halfword pair (0,1.0) read
// as f32 1.0f -> outputs were stored in the wrong dtype. Store f32 now.

typedef unsigned short u16;

__device__ inline float bf2f(u16 u) {
    union { unsigned int i; float f; } v; v.i = ((unsigned int)u) << 16; return v.f;
}
__device__ inline u16 f2bf(float f) {
    union { float f; unsigned int i; } v; v.f = f;
    unsigned int x = v.i;
    return (u16)((x + 0x7FFFu + ((x >> 16) & 1u)) >> 16);   // RNE
}

// Tiled GEMM: C[M,N] = epi( stage(A) @ Bw + bias ), tile 64x64, BK=16,
// 256 threads, 4x4 acc/thread. Bw: f32 KxN. bias: f32[N]. M,N guarded.
// AMODE: 0 = A f32 [M,K]
//        1 = A bf16 [M,K] (module outs in ws)
//        2 = em-fused: A[r][k] = relu(em[r]*emW0[k] + emb0[k])  (all f32)
//        3 = product:  A[r][k] = Af32[r][k] * A2f32[r][k]
template<int AMODE, bool RELU_OUT, bool RELU_A, bool OUT_BF16>
__global__ __launch_bounds__(256) void gemm_kernel(
    const void* __restrict__ Av, const void* __restrict__ A2v,
    const float* __restrict__ Bw, const float* __restrict__ bias,
    const float* __restrict__ emp, const float* __restrict__ emW0,
    const float* __restrict__ emb0,
    void* __restrict__ Cv, int M, int N, int K)
{
    __shared__ float As[16][68];
    __shared__ float Bs[16][64];

    const int tid = threadIdx.x;
    const int tx = tid & 15, ty = tid >> 4;
    const int m0 = blockIdx.y * 64;
    const int n0 = blockIdx.x * 64;

    const int arow = tid >> 2;          // 0..63
    const int ak   = (tid & 3) * 4;     // 0,4,8,12
    const int brow = tid >> 4;          // 0..15
    const int bcol = (tid & 15) * 4;    // 0..60

    const bool vecN = ((N & 63) == 0);

    float acc[4][4];
#pragma unroll
    for (int i = 0; i < 4; i++)
#pragma unroll
        for (int j = 0; j < 4; j++) acc[i][j] = 0.f;

    for (int k0 = 0; k0 < K; k0 += 16) {
        float4 av;
        int r = m0 + arow; if (r >= M) r = M - 1;   // clamp: safe read, never stored
        if constexpr (AMODE == 0) {
            av = *(const float4*)((const float*)Av + (size_t)r * K + (k0 + ak));
        } else if constexpr (AMODE == 1) {
            ushort4 u = *(const ushort4*)((const u16*)Av + (size_t)r * K + (k0 + ak));
            av.x = bf2f(u.x); av.y = bf2f(u.y); av.z = bf2f(u.z); av.w = bf2f(u.w);
        } else if constexpr (AMODE == 2) {
            float emv = emp[r];
            float4 w = *(const float4*)(emW0 + k0 + ak);
            float4 b = *(const float4*)(emb0 + k0 + ak);
            av.x = fmaxf(emv * w.x + b.x, 0.f);
            av.y = fmaxf(emv * w.y + b.y, 0.f);
            av.z = fmaxf(emv * w.z + b.z, 0.f);
            av.w = fmaxf(emv * w.w + b.w, 0.f);
        } else {
            float4 a1 = *(const float4*)((const float*)Av  + (size_t)r * K + (k0 + ak));
            float4 a2 = *(const float4*)((const float*)A2v + (size_t)r * K + (k0 + ak));
            av.x = a1.x * a2.x; av.y = a1.y * a2.y;
            av.z = a1.z * a2.z; av.w = a1.w * a2.w;
        }
        if (RELU_A) {
            av.x = fmaxf(av.x, 0.f); av.y = fmaxf(av.y, 0.f);
            av.z = fmaxf(av.z, 0.f); av.w = fmaxf(av.w, 0.f);
        }
        As[ak + 0][arow] = av.x; As[ak + 1][arow] = av.y;
        As[ak + 2][arow] = av.z; As[ak + 3][arow] = av.w;

        if (vecN) {
            float4 b = *(const float4*)(Bw + (size_t)(k0 + brow) * N + (n0 + bcol));
            Bs[brow][bcol + 0] = b.x; Bs[brow][bcol + 1] = b.y;
            Bs[brow][bcol + 2] = b.z; Bs[brow][bcol + 3] = b.w;
        } else {
#pragma unroll
            for (int j = 0; j < 4; j++) {
                int c = n0 + bcol + j;
                Bs[brow][bcol + j] = (c < N) ? Bw[(size_t)(k0 + brow) * N + c] : 0.f;
            }
        }
        __syncthreads();

#pragma unroll
        for (int kk = 0; kk < 16; kk++) {
            float4 a = *(const float4*)&As[kk][ty * 4];
            float4 b = *(const float4*)&Bs[kk][tx * 4];
            acc[0][0] += a.x * b.x; acc[0][1] += a.x * b.y; acc[0][2] += a.x * b.z; acc[0][3] += a.x * b.w;
            acc[1][0] += a.y * b.x; acc[1][1] += a.y * b.y; acc[1][2] += a.y * b.z; acc[1][3] += a.y * b.w;
            acc[2][0] += a.z * b.x; acc[2][1] += a.z * b.y; acc[2][2] += a.z * b.z; acc[2][3] += a.z * b.w;
            acc[3][0] += a.w * b.x; acc[3][1] += a.w * b.y; acc[3][2] += a.w * b.z; acc[3][3] += a.w * b.w;
        }
        __syncthreads();
    }

#pragma unroll
    for (int i = 0; i < 4; i++) {
        int r = m0 + ty * 4 + i;
#pragma unroll
        for (int j = 0; j < 4; j++) {
            int c = n0 + tx * 4 + j;
            if (r < M && c < N) {
                float v = acc[i][j] + bias[c];
                if (RELU_OUT) v = fmaxf(v, 0.f);
                if (OUT_BF16) ((u16*)Cv)[(size_t)r * N + c] = f2bf(v);
                else          ((float*)Cv)[(size_t)r * N + c] = v;
            }
        }
    }
}

// per-row routing from f32 logits[b,0..9]; ALL outputs f32
__global__ __launch_bounds__(256) void routing_kernel(
    const float* __restrict__ logits, int Bc,
    float* __restrict__ gates, float* __restrict__ onehot,
    float* __restrict__ soft)
{
    int b = blockIdx.x * blockDim.x + threadIdx.x;
    if (b >= Bc) return;
    const float* l = logits + (size_t)b * 10;
    float* g  = gates  + (size_t)b * 10;
    float* oh = onehot + (size_t)b * 10;
    float* sf = soft   + (size_t)b * 10;

    g[0] = 1.f; oh[0] = 1.f; sf[0] = 1.f;

    int off = 1;
    for (int m = 2; m <= 4; m++) {
        float v[4];
        for (int i = 0; i < m; i++) v[i] = l[off + i];
        int i0 = 0;
        for (int i = 1; i < m; i++) if (v[i] > v[i0]) i0 = i;   // ties -> lower idx
        int i1 = (i0 == 0) ? 1 : 0;
        for (int i = 0; i < m; i++) if (i != i0 && v[i] > v[i1]) i1 = i;
        float e1 = expf(v[i1] - v[i0]);   // <= 1
        float inv = 1.f / (1.f + e1);
        for (int i = 0; i < m; i++) { g[off + i] = 0.f; oh[off + i] = 0.f; }
        g[off + i0] = inv;
        g[off + i1] = e1 * inv;
        oh[off + i0] = 1.f; oh[off + i1] = 1.f;
        float mall = v[0];
        for (int i = 1; i < m; i++) mall = fmaxf(mall, v[i]);
        float ex[4]; float se = 0.f;
        for (int i = 0; i < m; i++) { ex[i] = expf(v[i] - mall); se += ex[i]; }
        float rse = 1.f / se;
        for (int i = 0; i < m; i++) sf[off + i] = ex[i] * rse;
        off += m;
    }
}

// dst[b,h] = sum_{m<cnt} gates[b,goff+m] * o_m[b,h]  (gates f32, o bf16, dst bf16)
__global__ __launch_bounds__(256) void combine_kernel(
    const float* __restrict__ gates, int goff, int cnt, int n4, int H,
    const u16* __restrict__ o0, const u16* __restrict__ o1,
    const u16* __restrict__ o2, const u16* __restrict__ o3,
    u16* __restrict__ dst)
{
    int i4 = blockIdx.x * blockDim.x + threadIdx.x;
    if (i4 >= n4) return;
    int b = (i4 * 4) / H;
    const float* gp = gates + (size_t)b * 10 + goff;
    ushort4 a = ((const ushort4*)o0)[i4];
    float g0 = gp[0];
    float4 acc;
    acc.x = g0 * bf2f(a.x); acc.y = g0 * bf2f(a.y);
    acc.z = g0 * bf2f(a.z); acc.w = g0 * bf2f(a.w);
    if (cnt > 1) {
        float g1 = gp[1]; ushort4 u = ((const ushort4*)o1)[i4];
        acc.x += g1 * bf2f(u.x); acc.y += g1 * bf2f(u.y);
        acc.z += g1 * bf2f(u.z); acc.w += g1 * bf2f(u.w);
    }
    if (cnt > 2) {
        float g2 = gp[2]; ushort4 u = ((const ushort4*)o2)[i4];
        acc.x += g2 * bf2f(u.x); acc.y += g2 * bf2f(u.y);
        acc.z += g2 * bf2f(u.z); acc.w += g2 * bf2f(u.w);
    }
    if (cnt > 3) {
        float g3 = gp[3]; ushort4 u = ((const ushort4*)o3)[i4];
        acc.x += g3 * bf2f(u.x); acc.y += g3 * bf2f(u.y);
        acc.z += g3 * bf2f(u.z); acc.w += g3 * bf2f(u.w);
    }
    ushort4 r;
    r.x = f2bf(acc.x); r.y = f2bf(acc.y); r.z = f2bf(acc.z); r.w = f2bf(acc.w);
    ((ushort4*)dst)[i4] = r;
}

extern "C" void kernel_launch(void* const* d_in, const int* in_sizes, int n_in,
                              void* d_out, int out_size, void* d_ws, size_t ws_size,
                              hipStream_t stream) {
    const float* x       = (const float*)d_in[0];
    const float* em      = (const float*)d_in[1];
    const float* base_W0 = (const float*)d_in[2];
    const float* base_b0 = (const float*)d_in[3];
    const float* base_W1 = (const float*)d_in[4];
    const float* base_b1 = (const float*)d_in[5];
    const float* em_W0   = (const float*)d_in[6];
    const float* em_b0   = (const float*)d_in[7];
    const float* em_W1   = (const float*)d_in[8];
    const float* em_b1   = (const float*)d_in[9];
    const float* gate_W0 = (const float*)d_in[10];
    const float* gate_b0 = (const float*)d_in[11];
    const float* gate_W1 = (const float*)d_in[12];
    const float* gate_b1 = (const float*)d_in[13];
    const float* fc_W    = (const float*)d_in[14];
    const float* fc_b    = (const float*)d_in[15];
    const float* last_W  = (const float*)d_in[16];
    const float* last_b  = (const float*)d_in[17];

    // ---- derive dims from in_sizes ----
    const int H    = in_sizes[3];              // base_b0: (H,)
    const int INF  = in_sizes[2] / H;          // base_W0: (IN,H)
    const int B    = in_sizes[0] / INF;        // x: (B,IN)
    const int EMH  = in_sizes[7];              // em_b0: (EMH,)
    const int GH   = in_sizes[11];             // gate_b0: (GH,)
    const int NOUT = in_sizes[17];             // last_b: (OUT,)

    float* out = (float*)d_out;                       // F32 OUTPUT BUFFER
    float* o_final  = out;                            // B x NOUT
    float* o_gates  = out + (size_t)B * NOUT;         // B x 10
    float* o_onehot = o_gates + (size_t)B * 10;
    float* o_soft   = o_onehot + (size_t)B * 10;

    // per-row ws bytes: R0 4H + R1 4H + R2 4GH + LG 40
    const size_t perRow = (size_t)8 * H + (size_t)4 * GH + 40;
    int Bc = ((B + 63) / 64) * 64;
    while (Bc > 64 && (size_t)Bc * perRow > ws_size) Bc >>= 1;

    char* wsb = (char*)d_ws;
    float* R0 = (float*)wsb;                                   // Bc*H f32: h0 -> e ; later O0|O1 bf16
    float* R1 = (float*)(wsb + (size_t)Bc * 4 * H);            // Bc*H f32: base_out ; later O2|O3 bf16
    float* R2 = (float*)(wsb + (size_t)Bc * 8 * H);            // Bc*GH f32: g0 ; later D bf16
    float* LG = (float*)(wsb + (size_t)Bc * (8 * H + 4 * GH)); // Bc*10 f32
    u16* O0 = (u16*)R0;
    u16* O1 = O0 + (size_t)Bc * H;
    u16* O2 = (u16*)R1;
    u16* O3 = O2 + (size_t)Bc * H;
    u16* D  = (u16*)R2;                                        // Bc*H bf16 (fits: 4*GH >= 2*H)

    dim3 blk(256);
    const size_t fc1 = (size_t)H * H;

    for (int c0 = 0; c0 < B; c0 += Bc) {
        const int Bcur = (B - c0 < Bc) ? (B - c0) : Bc;
        const float* xc  = x + (size_t)c0 * INF;
        const float* emc = em + c0;
        float* ofin = o_final  + (size_t)c0 * NOUT;
        float* ogat = o_gates  + (size_t)c0 * 10;
        float* ooh  = o_onehot + (size_t)c0 * 10;
        float* osf  = o_soft   + (size_t)c0 * 10;

        auto grid = [&](int N) { return dim3((unsigned)((N + 63) / 64), (unsigned)((Bcur + 63) / 64)); };
        const int n4 = Bcur * H / 4;
        const dim3 cgrid((unsigned)((n4 + 255) / 256));

        // h0 = relu(x @ base_W0 + base_b0)              -> R0
        gemm_kernel<0, true, false, false><<<grid(H), blk, 0, stream>>>(
            xc, nullptr, base_W0, base_b0, nullptr, nullptr, nullptr, R0, Bcur, H, INF);
        // base_out = h0 @ base_W1 + base_b1             -> R1
        gemm_kernel<0, false, false, false><<<grid(H), blk, 0, stream>>>(
            R0, nullptr, base_W1, base_b1, nullptr, nullptr, nullptr, R1, Bcur, H, H);
        // e = relu(relu(em*emW0+emb0) @ em_W1 + em_b1)  -> R0  [em path fused]
        gemm_kernel<2, true, false, false><<<grid(H), blk, 0, stream>>>(
            nullptr, nullptr, em_W1, em_b1, emc, em_W0, em_b0, R0, Bcur, H, EMH);
        // g0 = relu((e*base_out) @ gate_W0 + gate_b0)   -> R2  [gate_in fused]
        gemm_kernel<3, true, false, false><<<grid(GH), blk, 0, stream>>>(
            R0, R1, gate_W0, gate_b0, nullptr, nullptr, nullptr, R2, Bcur, GH, H);
        // logits = g0 @ gate_W1 + gate_b1               -> LG
        gemm_kernel<0, false, false, false><<<grid(10), blk, 0, stream>>>(
            R2, nullptr, gate_W1, gate_b1, nullptr, nullptr, nullptr, LG, Bcur, 10, GH);
        // routing (f32 outputs; gates doubles as combine coefficients)
        routing_kernel<<<dim3((unsigned)((Bcur + 255) / 256)), blk, 0, stream>>>(LG, Bcur, ogat, ooh, osf);
        // out0 = relu(relu(base_out) @ fc_W0 + fc_b0)   -> O0 (bf16 in ws)
        gemm_kernel<0, true, true, true><<<grid(H), blk, 0, stream>>>(
            R1, nullptr, fc_W, fc_b, nullptr, nullptr, nullptr, (void*)O0, Bcur, H, H);
        // out1 (m=1 gate == 1.0 -> input = O0)          -> O1
        gemm_kernel<1, true, false, true><<<grid(H), blk, 0, stream>>>(
            O0, nullptr, fc_W + fc1, fc_b + H, nullptr, nullptr, nullptr, (void*)O1, Bcur, H, H);
        // inp2 -> D ; out2 -> O2
        combine_kernel<<<cgrid, blk, 0, stream>>>(ogat, 1, 2, n4, H, O0, O1, O1, O1, D);
        gemm_kernel<1, true, false, true><<<grid(H), blk, 0, stream>>>(
            D, nullptr, fc_W + 2 * fc1, fc_b + 2 * H, nullptr, nullptr, nullptr, (void*)O2, Bcur, H, H);
        // inp3 -> D ; out3 -> O3
        combine_kernel<<<cgrid, blk, 0, stream>>>(ogat, 3, 3, n4, H, O0, O1, O2, O2, D);
        gemm_kernel<1, true, false, true><<<grid(H), blk, 0, stream>>>(
            D, nullptr, fc_W + 3 * fc1, fc_b + 3 * H, nullptr, nullptr, nullptr, (void*)O3, Bcur, H, H);
        // last_out -> D ; final -> ofin (F32)
        combine_kernel<<<cgrid, blk, 0, stream>>>(ogat, 6, 4, n4, H, O0, O1, O2, O3, D);
        gemm_kernel<1, false, false, false><<<grid(NOUT), blk, 0, stream>>>(
            D, nullptr, last_W, last_b, nullptr, nullptr, nullptr, (void*)ofin, Bcur, NOUT, H);
    }
}

// Round 9
// 877.367 us; speedup vs baseline: 1.7987x; 1.7987x over previous
//
#include <hip/hip_runtime.h>
#include <hip/hip_bf16.h>

// DepthRouteNet — round 8: bf16 MFMA for the fc chain (68.7 of 100 GFLOP).
// Routing-feeding path (base/em/gate) stays f32 vector (top-k flip = 1.0 error).
// fc_W transposed+cast to bf16 [N][K] once per launch; 128x128 MFMA tiles.

typedef unsigned short u16;
typedef __attribute__((ext_vector_type(8))) short bf16x8;
typedef __attribute__((ext_vector_type(4))) float f32x4;

__device__ inline float bf2f(u16 u) {
    union { unsigned int i; float f; } v; v.i = ((unsigned int)u) << 16; return v.f;
}
__device__ inline u16 f2bf(float f) {
    union { float f; unsigned int i; } v; v.f = f;
    unsigned int x = v.i;
    return (u16)((x + 0x7FFFu + ((x >> 16) & 1u)) >> 16);   // RNE
}

// ---------------- f32 vector GEMM (routing path; unchanged from R7) ----------
// AMODE: 0=A f32; 1=A bf16; 2=em-fused; 3=product of two f32
template<int AMODE, bool RELU_OUT, bool RELU_A, bool OUT_BF16>
__global__ __launch_bounds__(256) void gemm_kernel(
    const void* __restrict__ Av, const void* __restrict__ A2v,
    const float* __restrict__ Bw, const float* __restrict__ bias,
    const float* __restrict__ emp, const float* __restrict__ emW0,
    const float* __restrict__ emb0,
    void* __restrict__ Cv, int M, int N, int K)
{
    __shared__ float As[16][68];
    __shared__ float Bs[16][64];

    const int tid = threadIdx.x;
    const int tx = tid & 15, ty = tid >> 4;
    const int m0 = blockIdx.y * 64;
    const int n0 = blockIdx.x * 64;

    const int arow = tid >> 2;
    const int ak   = (tid & 3) * 4;
    const int brow = tid >> 4;
    const int bcol = (tid & 15) * 4;

    const bool vecN = ((N & 63) == 0);

    float acc[4][4];
#pragma unroll
    for (int i = 0; i < 4; i++)
#pragma unroll
        for (int j = 0; j < 4; j++) acc[i][j] = 0.f;

    for (int k0 = 0; k0 < K; k0 += 16) {
        float4 av;
        int r = m0 + arow; if (r >= M) r = M - 1;
        if constexpr (AMODE == 0) {
            av = *(const float4*)((const float*)Av + (size_t)r * K + (k0 + ak));
        } else if constexpr (AMODE == 1) {
            ushort4 u = *(const ushort4*)((const u16*)Av + (size_t)r * K + (k0 + ak));
            av.x = bf2f(u.x); av.y = bf2f(u.y); av.z = bf2f(u.z); av.w = bf2f(u.w);
        } else if constexpr (AMODE == 2) {
            float emv = emp[r];
            float4 w = *(const float4*)(emW0 + k0 + ak);
            float4 b = *(const float4*)(emb0 + k0 + ak);
            av.x = fmaxf(emv * w.x + b.x, 0.f);
            av.y = fmaxf(emv * w.y + b.y, 0.f);
            av.z = fmaxf(emv * w.z + b.z, 0.f);
            av.w = fmaxf(emv * w.w + b.w, 0.f);
        } else {
            float4 a1 = *(const float4*)((const float*)Av  + (size_t)r * K + (k0 + ak));
            float4 a2 = *(const float4*)((const float*)A2v + (size_t)r * K + (k0 + ak));
            av.x = a1.x * a2.x; av.y = a1.y * a2.y;
            av.z = a1.z * a2.z; av.w = a1.w * a2.w;
        }
        if (RELU_A) {
            av.x = fmaxf(av.x, 0.f); av.y = fmaxf(av.y, 0.f);
            av.z = fmaxf(av.z, 0.f); av.w = fmaxf(av.w, 0.f);
        }
        As[ak + 0][arow] = av.x; As[ak + 1][arow] = av.y;
        As[ak + 2][arow] = av.z; As[ak + 3][arow] = av.w;

        if (vecN) {
            float4 b = *(const float4*)(Bw + (size_t)(k0 + brow) * N + (n0 + bcol));
            Bs[brow][bcol + 0] = b.x; Bs[brow][bcol + 1] = b.y;
            Bs[brow][bcol + 2] = b.z; Bs[brow][bcol + 3] = b.w;
        } else {
#pragma unroll
            for (int j = 0; j < 4; j++) {
                int c = n0 + bcol + j;
                Bs[brow][bcol + j] = (c < N) ? Bw[(size_t)(k0 + brow) * N + c] : 0.f;
            }
        }
        __syncthreads();

#pragma unroll
        for (int kk = 0; kk < 16; kk++) {
            float4 a = *(const float4*)&As[kk][ty * 4];
            float4 b = *(const float4*)&Bs[kk][tx * 4];
            acc[0][0] += a.x * b.x; acc[0][1] += a.x * b.y; acc[0][2] += a.x * b.z; acc[0][3] += a.x * b.w;
            acc[1][0] += a.y * b.x; acc[1][1] += a.y * b.y; acc[1][2] += a.y * b.z; acc[1][3] += a.y * b.w;
            acc[2][0] += a.z * b.x; acc[2][1] += a.z * b.y; acc[2][2] += a.z * b.z; acc[2][3] += a.z * b.w;
            acc[3][0] += a.w * b.x; acc[3][1] += a.w * b.y; acc[3][2] += a.w * b.z; acc[3][3] += a.w * b.w;
        }
        __syncthreads();
    }

#pragma unroll
    for (int i = 0; i < 4; i++) {
        int r = m0 + ty * 4 + i;
#pragma unroll
        for (int j = 0; j < 4; j++) {
            int c = n0 + tx * 4 + j;
            if (r < M && c < N) {
                float v = acc[i][j] + bias[c];
                if (RELU_OUT) v = fmaxf(v, 0.f);
                if (OUT_BF16) ((u16*)Cv)[(size_t)r * N + c] = f2bf(v);
                else          ((float*)Cv)[(size_t)r * N + c] = v;
            }
        }
    }
}

// ---------------- MFMA bf16 GEMM for fc layers -------------------------------
// A: bf16 [M,K]; BT: bf16 [N,K] (pre-transposed weight); C: bf16 [M,N].
// C = relu(A @ BT^T + bias). 128x128 tile, BK=32, 4 waves, 4x4 16x16 frags/wave.
// LDS rows padded to 40 shorts (80B) to break power-of-2 bank aliasing.
__global__ __launch_bounds__(256) void mfma_fc_kernel(
    const short* __restrict__ A, const short* __restrict__ BT,
    const float* __restrict__ bias, short* __restrict__ C,
    int M, int N, int K)
{
    __shared__ short As[128 * 40];
    __shared__ short Bs[128 * 40];
    const int tid = threadIdx.x;
    const int wave = tid >> 6, lane = tid & 63;
    const int m0 = blockIdx.y * 128, n0 = blockIdx.x * 128;
    const int quad = lane >> 4, l16 = lane & 15;
    const int mq = (wave >> 1) * 64, nq = (wave & 1) * 64;

    f32x4 acc[4][4] = {};

    for (int k0 = 0; k0 < K; k0 += 32) {
#pragma unroll
        for (int it = 0; it < 2; ++it) {
            int c = it * 256 + tid;          // 0..511 chunks of 8 shorts
            int row = c >> 2, seg = c & 3;
            int ra = m0 + row; if (ra >= M) ra = M - 1;
            *(bf16x8*)&As[row * 40 + seg * 8] =
                *(const bf16x8*)&A[(size_t)ra * K + k0 + seg * 8];
            int rb = n0 + row;               // N % 128 == 0 guaranteed by host
            *(bf16x8*)&Bs[row * 40 + seg * 8] =
                *(const bf16x8*)&BT[(size_t)rb * K + k0 + seg * 8];
        }
        __syncthreads();

        bf16x8 af[4], bfr[4];
#pragma unroll
        for (int i = 0; i < 4; ++i)
            af[i] = *(const bf16x8*)&As[(mq + i * 16 + l16) * 40 + quad * 8];
#pragma unroll
        for (int j = 0; j < 4; ++j)
            bfr[j] = *(const bf16x8*)&Bs[(nq + j * 16 + l16) * 40 + quad * 8];
#pragma unroll
        for (int i = 0; i < 4; ++i)
#pragma unroll
            for (int j = 0; j < 4; ++j)
                acc[i][j] = __builtin_amdgcn_mfma_f32_16x16x32_bf16(af[i], bfr[j], acc[i][j], 0, 0, 0);
        __syncthreads();
    }

    // C/D layout: col = lane&15, row = quad*4 + reg  [m89-verified]
#pragma unroll
    for (int i = 0; i < 4; ++i) {
#pragma unroll
        for (int j = 0; j < 4; ++j) {
            int col = n0 + nq + j * 16 + l16;
            float bv = bias[col];
#pragma unroll
            for (int r = 0; r < 4; ++r) {
                int row = m0 + mq + i * 16 + quad * 4 + r;
                if (row < M) {
                    float v = fmaxf(acc[i][j][r] + bv, 0.f);
                    C[(size_t)row * N + col] = (short)f2bf(v);
                }
            }
        }
    }
}

// transpose + f32->bf16: in [K,N] f32 -> out [N,K] bf16. K,N % 64 == 0.
__global__ __launch_bounds__(256) void transpose_kernel(
    const float* __restrict__ in, u16* __restrict__ out, int K, int N)
{
    __shared__ u16 T[64][65];
    int k0 = blockIdx.y * 64, n0 = blockIdx.x * 64;
    int t = threadIdx.x;
    int r = t >> 4, c4 = (t & 15) * 4;
#pragma unroll
    for (int i = 0; i < 4; ++i) {
        int kk = r + i * 16;
        float4 v = *(const float4*)&in[(size_t)(k0 + kk) * N + n0 + c4];
        T[c4 + 0][kk] = f2bf(v.x); T[c4 + 1][kk] = f2bf(v.y);
        T[c4 + 2][kk] = f2bf(v.z); T[c4 + 3][kk] = f2bf(v.w);
    }
    __syncthreads();
#pragma unroll
    for (int i = 0; i < 4; ++i) {
        int nn = r + i * 16;
        ushort4 o;
        o.x = T[nn][c4 + 0]; o.y = T[nn][c4 + 1];
        o.z = T[nn][c4 + 2]; o.w = T[nn][c4 + 3];
        *(ushort4*)&out[(size_t)(n0 + nn) * K + k0 + c4] = o;
    }
}

// relu + f32->bf16 convert (x4)
__global__ __launch_bounds__(256) void relu_cvt_kernel(
    const float* __restrict__ in, u16* __restrict__ out, int n4)
{
    int i = blockIdx.x * blockDim.x + threadIdx.x;
    if (i < n4) {
        float4 v = ((const float4*)in)[i];
        ushort4 o;
        o.x = f2bf(fmaxf(v.x, 0.f)); o.y = f2bf(fmaxf(v.y, 0.f));
        o.z = f2bf(fmaxf(v.z, 0.f)); o.w = f2bf(fmaxf(v.w, 0.f));
        ((ushort4*)out)[i] = o;
    }
}

// ---------------- routing / combine (unchanged from R7) ----------------------
__global__ __launch_bounds__(256) void routing_kernel(
    const float* __restrict__ logits, int Bc,
    float* __restrict__ gates, float* __restrict__ onehot,
    float* __restrict__ soft)
{
    int b = blockIdx.x * blockDim.x + threadIdx.x;
    if (b >= Bc) return;
    const float* l = logits + (size_t)b * 10;
    float* g  = gates  + (size_t)b * 10;
    float* oh = onehot + (size_t)b * 10;
    float* sf = soft   + (size_t)b * 10;

    g[0] = 1.f; oh[0] = 1.f; sf[0] = 1.f;

    int off = 1;
    for (int m = 2; m <= 4; m++) {
        float v[4];
        for (int i = 0; i < m; i++) v[i] = l[off + i];
        int i0 = 0;
        for (int i = 1; i < m; i++) if (v[i] > v[i0]) i0 = i;
        int i1 = (i0 == 0) ? 1 : 0;
        for (int i = 0; i < m; i++) if (i != i0 && v[i] > v[i1]) i1 = i;
        float e1 = expf(v[i1] - v[i0]);
        float inv = 1.f / (1.f + e1);
        for (int i = 0; i < m; i++) { g[off + i] = 0.f; oh[off + i] = 0.f; }
        g[off + i0] = inv;
        g[off + i1] = e1 * inv;
        oh[off + i0] = 1.f; oh[off + i1] = 1.f;
        float mall = v[0];
        for (int i = 1; i < m; i++) mall = fmaxf(mall, v[i]);
        float ex[4]; float se = 0.f;
        for (int i = 0; i < m; i++) { ex[i] = expf(v[i] - mall); se += ex[i]; }
        float rse = 1.f / se;
        for (int i = 0; i < m; i++) sf[off + i] = ex[i] * rse;
        off += m;
    }
}

__global__ __launch_bounds__(256) void combine_kernel(
    const float* __restrict__ gates, int goff, int cnt, int n4, int H,
    const u16* __restrict__ o0, const u16* __restrict__ o1,
    const u16* __restrict__ o2, const u16* __restrict__ o3,
    u16* __restrict__ dst)
{
    int i4 = blockIdx.x * blockDim.x + threadIdx.x;
    if (i4 >= n4) return;
    int b = (i4 * 4) / H;
    const float* gp = gates + (size_t)b * 10 + goff;
    ushort4 a = ((const ushort4*)o0)[i4];
    float g0 = gp[0];
    float4 acc;
    acc.x = g0 * bf2f(a.x); acc.y = g0 * bf2f(a.y);
    acc.z = g0 * bf2f(a.z); acc.w = g0 * bf2f(a.w);
    if (cnt > 1) {
        float g1 = gp[1]; ushort4 u = ((const ushort4*)o1)[i4];
        acc.x += g1 * bf2f(u.x); acc.y += g1 * bf2f(u.y);
        acc.z += g1 * bf2f(u.z); acc.w += g1 * bf2f(u.w);
    }
    if (cnt > 2) {
        float g2 = gp[2]; ushort4 u = ((const ushort4*)o2)[i4];
        acc.x += g2 * bf2f(u.x); acc.y += g2 * bf2f(u.y);
        acc.z += g2 * bf2f(u.z); acc.w += g2 * bf2f(u.w);
    }
    if (cnt > 3) {
        float g3 = gp[3]; ushort4 u = ((const ushort4*)o3)[i4];
        acc.x += g3 * bf2f(u.x); acc.y += g3 * bf2f(u.y);
        acc.z += g3 * bf2f(u.z); acc.w += g3 * bf2f(u.w);
    }
    ushort4 r;
    r.x = f2bf(acc.x); r.y = f2bf(acc.y); r.z = f2bf(acc.z); r.w = f2bf(acc.w);
    ((ushort4*)dst)[i4] = r;
}

extern "C" void kernel_launch(void* const* d_in, const int* in_sizes, int n_in,
                              void* d_out, int out_size, void* d_ws, size_t ws_size,
                              hipStream_t stream) {
    const float* x       = (const float*)d_in[0];
    const float* em      = (const float*)d_in[1];
    const float* base_W0 = (const float*)d_in[2];
    const float* base_b0 = (const float*)d_in[3];
    const float* base_W1 = (const float*)d_in[4];
    const float* base_b1 = (const float*)d_in[5];
    const float* em_W0   = (const float*)d_in[6];
    const float* em_b0   = (const float*)d_in[7];
    const float* em_W1   = (const float*)d_in[8];
    const float* em_b1   = (const float*)d_in[9];
    const float* gate_W0 = (const float*)d_in[10];
    const float* gate_b0 = (const float*)d_in[11];
    const float* gate_W1 = (const float*)d_in[12];
    const float* gate_b1 = (const float*)d_in[13];
    const float* fc_W    = (const float*)d_in[14];
    const float* fc_b    = (const float*)d_in[15];
    const float* last_W  = (const float*)d_in[16];
    const float* last_b  = (const float*)d_in[17];

    const int H    = in_sizes[3];
    const int INF  = in_sizes[2] / H;
    const int B    = in_sizes[0] / INF;
    const int EMH  = in_sizes[7];
    const int GH   = in_sizes[11];
    const int NOUT = in_sizes[17];

    float* out = (float*)d_out;
    float* o_final  = out;
    float* o_gates  = out + (size_t)B * NOUT;
    float* o_onehot = o_gates + (size_t)B * 10;
    float* o_soft   = o_onehot + (size_t)B * 10;

    // MFMA path requires H%128==0 (N tiles), H%32==0 (K tiles), H%64==0 (transpose)
    const size_t fixed = (size_t)8 * H * H;      // 4 transposed fc weights, bf16
    const size_t perRow = (size_t)8 * H + (size_t)4 * GH + 40;
    bool useMfma = (H % 128 == 0) && (ws_size > fixed + 64 * perRow);

    int Bc = ((B + 63) / 64) * 64;
    size_t avail = ws_size - (useMfma ? fixed : 0);
    while (Bc > 64 && (size_t)Bc * perRow > avail) Bc >>= 1;

    char* wsb = (char*)d_ws;
    u16* WT = (u16*)wsb;                         // [4][H][H] bf16 transposed (mfma only)
    char* rows = wsb + (useMfma ? fixed : 0);
    float* R0 = (float*)rows;                                    // Bc*H f32: h0 -> e ; O0|O1 bf16
    float* R1 = (float*)(rows + (size_t)Bc * 4 * H);             // Bc*H f32: base_out ; O2|O3 bf16
    float* R2 = (float*)(rows + (size_t)Bc * 8 * H);             // Bc*GH f32: g0 ; T/D bf16
    float* LG = (float*)(rows + (size_t)Bc * (8 * H + 4 * GH));  // Bc*10 f32
    u16* O0 = (u16*)R0;
    u16* O1 = O0 + (size_t)Bc * H;
    u16* O2 = (u16*)R1;
    u16* O3 = O2 + (size_t)Bc * H;
    u16* D  = (u16*)R2;                          // also T = relu(base_out) bf16

    dim3 blk(256);
    const size_t fc1 = (size_t)H * H;

    if (useMfma) {
        dim3 tgrid((unsigned)(H / 64), (unsigned)(H / 64));
        for (int i = 0; i < 4; ++i)
            transpose_kernel<<<tgrid, blk, 0, stream>>>(fc_W + (size_t)i * fc1, WT + (size_t)i * fc1, H, H);
    }

    for (int c0 = 0; c0 < B; c0 += Bc) {
        const int Bcur = (B - c0 < Bc) ? (B - c0) : Bc;
        const float* xc  = x + (size_t)c0 * INF;
        const float* emc = em + c0;
        float* ofin = o_final  + (size_t)c0 * NOUT;
        float* ogat = o_gates  + (size_t)c0 * 10;
        float* ooh  = o_onehot + (size_t)c0 * 10;
        float* osf  = o_soft   + (size_t)c0 * 10;

        auto grid = [&](int N) { return dim3((unsigned)((N + 63) / 64), (unsigned)((Bcur + 63) / 64)); };
        const dim3 mgrid((unsigned)(H / 128), (unsigned)((Bcur + 127) / 128));
        const int n4 = Bcur * H / 4;
        const dim3 cgrid((unsigned)((n4 + 255) / 256));

        // f32 routing path
        gemm_kernel<0, true, false, false><<<grid(H), blk, 0, stream>>>(
            xc, nullptr, base_W0, base_b0, nullptr, nullptr, nullptr, R0, Bcur, H, INF);
        gemm_kernel<0, false, false, false><<<grid(H), blk, 0, stream>>>(
            R0, nullptr, base_W1, base_b1, nullptr, nullptr, nullptr, R1, Bcur, H, H);
        gemm_kernel<2, true, false, false><<<grid(H), blk, 0, stream>>>(
            nullptr, nullptr, em_W1, em_b1, emc, em_W0, em_b0, R0, Bcur, H, EMH);
        gemm_kernel<3, true, false, false><<<grid(GH), blk, 0, stream>>>(
            R0, R1, gate_W0, gate_b0, nullptr, nullptr, nullptr, R2, Bcur, GH, H);
        gemm_kernel<0, false, false, false><<<grid(10), blk, 0, stream>>>(
            R2, nullptr, gate_W1, gate_b1, nullptr, nullptr, nullptr, LG, Bcur, 10, GH);
        routing_kernel<<<dim3((unsigned)((Bcur + 255) / 256)), blk, 0, stream>>>(LG, Bcur, ogat, ooh, osf);

        if (useMfma) {
            // T = relu(base_out) bf16 -> R2 region (g0 dead)
            relu_cvt_kernel<<<cgrid, blk, 0, stream>>>(R1, D, n4);
            // out0..out3 via MFMA
            mfma_fc_kernel<<<mgrid, blk, 0, stream>>>(
                (const short*)D, (const short*)WT, fc_b, (short*)O0, Bcur, H, H);
            mfma_fc_kernel<<<mgrid, blk, 0, stream>>>(
                (const short*)O0, (const short*)(WT + fc1), fc_b + H, (short*)O1, Bcur, H, H);
            combine_kernel<<<cgrid, blk, 0, stream>>>(ogat, 1, 2, n4, H, O0, O1, O1, O1, D);
            mfma_fc_kernel<<<mgrid, blk, 0, stream>>>(
                (const short*)D, (const short*)(WT + 2 * fc1), fc_b + 2 * H, (short*)O2, Bcur, H, H);
            combine_kernel<<<cgrid, blk, 0, stream>>>(ogat, 3, 3, n4, H, O0, O1, O2, O2, D);
            mfma_fc_kernel<<<mgrid, blk, 0, stream>>>(
                (const short*)D, (const short*)(WT + 3 * fc1), fc_b + 3 * H, (short*)O3, Bcur, H, H);
        } else {
            gemm_kernel<0, true, true, true><<<grid(H), blk, 0, stream>>>(
                R1, nullptr, fc_W, fc_b, nullptr, nullptr, nullptr, (void*)O0, Bcur, H, H);
            gemm_kernel<1, true, false, true><<<grid(H), blk, 0, stream>>>(
                O0, nullptr, fc_W + fc1, fc_b + H, nullptr, nullptr, nullptr, (void*)O1, Bcur, H, H);
            combine_kernel<<<cgrid, blk, 0, stream>>>(ogat, 1, 2, n4, H, O0, O1, O1, O1, D);
            gemm_kernel<1, true, false, true><<<grid(H), blk, 0, stream>>>(
                D, nullptr, fc_W + 2 * fc1, fc_b + 2 * H, nullptr, nullptr, nullptr, (void*)O2, Bcur, H, H);
            combine_kernel<<<cgrid, blk, 0, stream>>>(ogat, 3, 3, n4, H, O0, O1, O2, O2, D);
            gemm_kernel<1, true, false, true><<<grid(H), blk, 0, stream>>>(
                D, nullptr, fc_W + 3 * fc1, fc_b + 3 * H, nullptr, nullptr, nullptr, (void*)O3, Bcur, H, H);
        }
        // last_out -> D ; final -> ofin (f32)
        combine_kernel<<<cgrid, blk, 0, stream>>>(ogat, 6, 4, n4, H, O0, O1, O2, O3, D);
        gemm_kernel<1, false, false, false><<<grid(NOUT), blk, 0, stream>>>(
            D, nullptr, last_W, last_b, nullptr, nullptr, nullptr, (void*)ofin, Bcur, NOUT, H);
    }
}